// Round 1
// baseline (337.790 us; speedup 1.0000x reference)
//
#include <hip/hip_runtime.h>

namespace {
constexpr int Bn = 16, Cn = 8, Hn = 512, Wn = 512;
constexpr int HW  = Hn * Wn;        // 262144
constexpr int CHW = Cn * HW;        // 2097152
constexpr int NCOL = Bn * Wn;       // 8192 dice columns
constexpr int NBLK = 8 * 8 * 16;    // grid of main kernel = 1024 blocks

__device__ __forceinline__ float fsigmoid(float x) {
    return __builtin_amdgcn_rcpf(1.0f + __expf(-x));
}
} // namespace

// DIRS per reference: dx horizontal shift, dy vertical; shifted[i] uses channel 7-i.
// Since DIRS[7-c] = -DIRS[c], vote[i] = p[i] * sigmoid(c_map[ch=7-i][h+DY[7-i]][w+DX[7-i]])
// i.e. neighbor of channel c lives at (h+DY[c], w+DX[c]) and pairs as n[7-i].

__global__ __launch_bounds__(256) void bicon_main(
    const float* __restrict__ c_map,
    const int*   __restrict__ target,
    const int*   __restrict__ con_target,
    float* __restrict__ col_i,   // [NCOL] sum_h target
    float* __restrict__ col_j,   // [NCOL] sum_h final_pred
    float* __restrict__ col_x,   // [NCOL] sum_h target*final_pred
    double* __restrict__ bscal)  // [NBLK][4] per-block {conmap, bimap, bce, dec} sums
{
    constexpr int DX[8] = {1, 0, -1, 1, -1, 1, 0, -1};
    constexpr int DY[8] = {1, 1, 1, 0, 0, -1, -1, -1};

    const int tx = threadIdx.x;            // 0..63 : w within tile (== lane)
    const int ty = threadIdx.y;            // 0..3  : row phase (== wave id)
    const int b  = blockIdx.z;
    const int w  = (blockIdx.x << 6) + tx;
    const int h0 = blockIdx.y << 6;        // 64-row chunk

    const float* cm = c_map      + (size_t)b * CHW;
    const int*   ct = con_target + (size_t)b * CHW;
    const int*   tg = target     + (size_t)b * HW;

    float s_con = 0.0f, s_bi = 0.0f, s_bce = 0.0f, s_dec = 0.0f;
    float ci = 0.0f, cj = 0.0f, cx = 0.0f;

    for (int hh = ty; hh < 64; hh += 4) {
        const int h    = h0 + hh;
        const int base = h * Wn + w;

        float p[8], nb[8];
        int   t8[8];
#pragma unroll
        for (int c = 0; c < 8; ++c) {
            const int idx = c * HW + base;
            p[c]  = fsigmoid(cm[idx]);
            t8[c] = ct[idx];
            const int hn = h + DY[c];
            const int wn = w + DX[c];
            float nv = 0.0f;
            if ((unsigned)hn < (unsigned)Hn && (unsigned)wn < (unsigned)Wn) {
                // same flat index + constant offset (folds into load immediate)
                nv = fsigmoid(cm[idx + DY[c] * Wn + DX[c]]);
            }
            nb[c] = nv;   // zero-pad shift semantics
        }
        const int t = tg[base];

        float vmax = -1.0f, vmin = 2.0f;
        int   sumc = 0;
        float it_con = 0.0f, it_bi = 0.0f;
#pragma unroll
        for (int i = 0; i < 8; ++i) {
            const float v = p[i] * nb[7 - i];
            vmax  = fmaxf(vmax, v);
            vmin  = fminf(vmin, v);
            sumc += t8[i];
            // t in {0,1}: t*log(p)+(1-t)*log(1-p) == log(t ? p : 1-p), clamped at -100
            it_con += fmaxf(__logf(t8[i] ? p[i] : 1.0f - p[i]), -100.0f);
            it_bi  += fmaxf(__logf(t8[i] ? v    : 1.0f - v),    -100.0f);
        }
        s_con += it_con;
        s_bi  += it_bi;
        s_bce += fmaxf(__logf(t ? vmax : 1.0f - vmax), -100.0f);
        // edge: 0 < sum(con_target over c) < 8 ; pred_min = edge ? vmin : 0
        if ((sumc > 0) & (sumc < 8)) {
            s_dec += fmaxf(__logf(1.0f - vmin), -100.0f);
        } // else log(1-0) = 0 contribution

        ci += (float)t;
        cj += vmax;
        cx += t ? vmax : 0.0f;
    }

    // ---- per-column dice partials: reduce over the 4 row-phase threads ----
    __shared__ float colred[3][4][64];
    colred[0][ty][tx] = ci;
    colred[1][ty][tx] = cj;
    colred[2][ty][tx] = cx;

    // ---- scalar sums: wave (== ty row) shuffle reduction ----
#pragma unroll
    for (int off = 32; off > 0; off >>= 1) {
        s_con += __shfl_down(s_con, off);
        s_bi  += __shfl_down(s_bi,  off);
        s_bce += __shfl_down(s_bce, off);
        s_dec += __shfl_down(s_dec, off);
    }
    __shared__ float wred[4][4];  // [wave][scalar]
    if (tx == 0) {
        wred[ty][0] = s_con;
        wred[ty][1] = s_bi;
        wred[ty][2] = s_bce;
        wred[ty][3] = s_dec;
    }
    __syncthreads();

    if (ty == 0) {
        const float a0 = colred[0][0][tx] + colred[0][1][tx] + colred[0][2][tx] + colred[0][3][tx];
        const float a1 = colred[1][0][tx] + colred[1][1][tx] + colred[1][2][tx] + colred[1][3][tx];
        const float a2 = colred[2][0][tx] + colred[2][1][tx] + colred[2][2][tx] + colred[2][3][tx];
        const int col = b * Wn + w;
        atomicAdd(&col_i[col], a0);   // 8 contenders per address — cheap
        atomicAdd(&col_j[col], a1);
        atomicAdd(&col_x[col], a2);
    }
    if (ty == 1 && tx < 4) {
        // per-block slot write (no contended double atomics)
        const int bid = (blockIdx.z * 8 + (int)blockIdx.y) * 8 + (int)blockIdx.x;
        bscal[bid * 4 + tx] =
            (double)(wred[0][tx] + wred[1][tx] + wred[2][tx] + wred[3][tx]);
    }
}

__global__ __launch_bounds__(256) void bicon_finish(
    const float* __restrict__ col_i,
    const float* __restrict__ col_j,
    const float* __restrict__ col_x,
    const double* __restrict__ bscal,
    float* __restrict__ out)
{
    const int tid = threadIdx.x;

    double dsum = 0.0;
    for (int idx = tid; idx < NCOL; idx += 256) {
        const float fi = col_i[idx], fj = col_j[idx], fx = col_x[idx];
        dsum += (double)(1.0f - (2.0f * fx + 0.001f) / (fi + fj + 0.001f));
    }
    double s0 = 0.0, s1 = 0.0, s2 = 0.0, s3 = 0.0;
    for (int s = tid; s < NBLK; s += 256) {
        s0 += bscal[s * 4 + 0];
        s1 += bscal[s * 4 + 1];
        s2 += bscal[s * 4 + 2];
        s3 += bscal[s * 4 + 3];
    }
#pragma unroll
    for (int off = 32; off > 0; off >>= 1) {
        dsum += __shfl_down(dsum, off);
        s0   += __shfl_down(s0, off);
        s1   += __shfl_down(s1, off);
        s2   += __shfl_down(s2, off);
        s3   += __shfl_down(s3, off);
    }
    __shared__ double red[5][4];
    const int wv = tid >> 6, ln = tid & 63;
    if (ln == 0) {
        red[0][wv] = dsum; red[1][wv] = s0; red[2][wv] = s1;
        red[3][wv] = s2;   red[4][wv] = s3;
    }
    __syncthreads();
    if (tid == 0) {
        const double dice   =  (red[0][0] + red[0][1] + red[0][2] + red[0][3]) / 8192.0;
        const double conmap = -(red[1][0] + red[1][1] + red[1][2] + red[1][3]) / 33554432.0;
        const double bimap  = -(red[2][0] + red[2][1] + red[2][2] + red[2][3]) / 33554432.0;
        const double bce    = -(red[3][0] + red[3][1] + red[3][2] + red[3][3]) / 4194304.0;
        const double dec    = -(red[4][0] + red[4][1] + red[4][2] + red[4][3]) / 4194304.0;
        out[0] = (float)(0.8 * conmap + dec + 0.2 * bimap + bce + dice);
    }
}

extern "C" void kernel_launch(void* const* d_in, const int* in_sizes, int n_in,
                              void* d_out, int out_size, void* d_ws, size_t ws_size,
                              hipStream_t stream) {
    const float* c_map      = (const float*)d_in[0];
    const int*   target     = (const int*)d_in[1];
    const int*   con_target = (const int*)d_in[2];
    float* out = (float*)d_out;

    char* ws = (char*)d_ws;
    float*  col_i = (float*)ws;                           // 8192 floats
    float*  col_j = col_i + NCOL;                         // 8192 floats
    float*  col_x = col_j + NCOL;                         // 8192 floats
    double* bscal = (double*)(ws + 3 * NCOL * sizeof(float)); // 1024*4 doubles (8B aligned)

    // zero only the atomically-accumulated column tables (bscal slots are
    // written unconditionally by every block)
    hipMemsetAsync(d_ws, 0, 3 * NCOL * sizeof(float), stream);

    dim3 grid(Wn / 64, Hn / 64, Bn);   // 8 x 8 x 16 = 1024 blocks
    dim3 block(64, 4);
    bicon_main<<<grid, block, 0, stream>>>(c_map, target, con_target,
                                           col_i, col_j, col_x, bscal);
    bicon_finish<<<1, 256, 0, stream>>>(col_i, col_j, col_x, bscal, out);
}